// Round 6
// baseline (116.774 us; speedup 1.0000x reference)
//
#include <hip/hip_runtime.h>

#define NQ     14
#define DIMQ   16384
#define NTROT  10
#define NWG    16          // WGs per team
#define NTHR   256
#define TEAM_PSI_BYTES 131072   // DIMQ * sizeof(float2)
#define CTRL_STRIDE    3072
#define PROBE_MAGIC    0x5A5A1234

typedef float vfloat4 __attribute__((ext_vector_type(4)));

struct Smem {
    float2 slab[1024];   // 8 KiB staging slab (also reused as float sumbuf)
    float2 tabLo[64];
    float2 tabHi[128];
    float  red[48];      // this WG's partial sums of the 42 constants
    int    fastmode;
};

// ================= mode-templated memory accessors ==========================
// F=true : sc0 only  -> coherent through the (shared) per-XCD L2
// F=false: sc0 sc1   -> device-coherent at MALL (same semantics as the proven
//                       R3/R4 agent-scope atomics)
template <bool F>
__device__ __forceinline__ void ld4c(const float2* p, float2 r[4]) {
    vfloat4 a, b;
    if constexpr (F)
        asm volatile("global_load_dwordx4 %0, %2, off sc0\n\t"
                     "global_load_dwordx4 %1, %2, off offset:16 sc0\n\t"
                     "s_waitcnt vmcnt(0)"
                     : "=&v"(a), "=&v"(b) : "v"(p) : "memory");
    else
        asm volatile("global_load_dwordx4 %0, %2, off sc0 sc1\n\t"
                     "global_load_dwordx4 %1, %2, off offset:16 sc0 sc1\n\t"
                     "s_waitcnt vmcnt(0)"
                     : "=&v"(a), "=&v"(b) : "v"(p) : "memory");
    r[0] = make_float2(a.x, a.y); r[1] = make_float2(a.z, a.w);
    r[2] = make_float2(b.x, b.y); r[3] = make_float2(b.z, b.w);
}
__device__ __forceinline__ float2 d2f2(double d) { union { double d; float2 f; } u; u.d = d; return u.f; }
__device__ __forceinline__ double f22d(float2 f) { union { double d; float2 f; } u; u.f = f; return u.d; }

template <bool F>
__device__ __forceinline__ void ld4s(const float2* p0, const float2* p1,
                                     const float2* p2, const float2* p3,
                                     float2 r[4]) {
    double d0, d1, d2, d3;
    if constexpr (F)
        asm volatile("global_load_dwordx2 %0, %4, off sc0\n\t"
                     "global_load_dwordx2 %1, %5, off sc0\n\t"
                     "global_load_dwordx2 %2, %6, off sc0\n\t"
                     "global_load_dwordx2 %3, %7, off sc0\n\t"
                     "s_waitcnt vmcnt(0)"
                     : "=&v"(d0), "=&v"(d1), "=&v"(d2), "=&v"(d3)
                     : "v"(p0), "v"(p1), "v"(p2), "v"(p3) : "memory");
    else
        asm volatile("global_load_dwordx2 %0, %4, off sc0 sc1\n\t"
                     "global_load_dwordx2 %1, %5, off sc0 sc1\n\t"
                     "global_load_dwordx2 %2, %6, off sc0 sc1\n\t"
                     "global_load_dwordx2 %3, %7, off sc0 sc1\n\t"
                     "s_waitcnt vmcnt(0)"
                     : "=&v"(d0), "=&v"(d1), "=&v"(d2), "=&v"(d3)
                     : "v"(p0), "v"(p1), "v"(p2), "v"(p3) : "memory");
    r[0] = d2f2(d0); r[1] = d2f2(d1); r[2] = d2f2(d2); r[3] = d2f2(d3);
}
template <bool F>
__device__ __forceinline__ void st2(float2* p, float2 v) {
    if constexpr (F)
        asm volatile("global_store_dwordx2 %0, %1, off sc0" :: "v"(p), "v"(f22d(v)) : "memory");
    else
        asm volatile("global_store_dwordx2 %0, %1, off sc0 sc1" :: "v"(p), "v"(f22d(v)) : "memory");
}
template <bool F>
__device__ __forceinline__ void stf(float* p, float v) {
    if constexpr (F)
        asm volatile("global_store_dword %0, %1, off sc0" :: "v"(p), "v"(v) : "memory");
    else
        asm volatile("global_store_dword %0, %1, off sc0 sc1" :: "v"(p), "v"(v) : "memory");
}
template <bool F>
__device__ __forceinline__ float ldf(const float* p) {
    float v;
    if constexpr (F)
        asm volatile("global_load_dword %0, %1, off sc0\n\ts_waitcnt vmcnt(0)"
                     : "=&v"(v) : "v"(p) : "memory");
    else
        asm volatile("global_load_dword %0, %1, off sc0 sc1\n\ts_waitcnt vmcnt(0)"
                     : "=&v"(v) : "v"(p) : "memory");
    return v;
}
template <bool F>
__device__ __forceinline__ void sti(int* p, int v) {
    if constexpr (F)
        asm volatile("global_store_dword %0, %1, off sc0" :: "v"(p), "v"(v) : "memory");
    else
        asm volatile("global_store_dword %0, %1, off sc0 sc1" :: "v"(p), "v"(v) : "memory");
}
template <bool F>
__device__ __forceinline__ int ldi(const int* p) {
    int v;
    if constexpr (F)
        asm volatile("global_load_dword %0, %1, off sc0\n\ts_waitcnt vmcnt(0)"
                     : "=&v"(v) : "v"(p) : "memory");
    else
        asm volatile("global_load_dword %0, %1, off sc0 sc1\n\ts_waitcnt vmcnt(0)"
                     : "=&v"(v) : "v"(p) : "memory");
    return v;
}

// Team barrier. EXPLICIT vmcnt drain: the compiler cannot track inline-asm
// stores, so we drain per-wave before __syncthreads, guaranteeing all psi
// stores are at the coherence point before the flag store.
template <bool F>
__device__ __forceinline__ void gbar(int* flags, int rank, int phase) {
    asm volatile("s_waitcnt vmcnt(0)" ::: "memory");
    __syncthreads();
    if (threadIdx.x < 64) {
        if (threadIdx.x == 0) sti<F>(&flags[rank], phase);
        for (;;) {
            int v = phase;
            if (threadIdx.x < NWG) v = ldi<F>(&flags[threadIdx.x]);
            if (__ballot(v >= phase) == ~0ull) break;
            __builtin_amdgcn_s_sleep(1);
        }
    }
    __syncthreads();
}

// ================= gate math (verbatim from the verified R4 kernel) =========
__device__ __forceinline__ float2 cmulf(float2 a, float2 b) {
    return make_float2(a.x * b.x - a.y * b.y, a.x * b.y + a.y * b.x);
}
__device__ __forceinline__ void bfly(float2& p0, float2& p1, float c, float s) {
    float2 n0 = make_float2(c * p0.x + s * p1.y, c * p0.y - s * p1.x);
    float2 n1 = make_float2(c * p1.x + s * p0.y, c * p1.y - s * p0.x);
    p0 = n0; p1 = n1;
}
__device__ __forceinline__ void bfly_shfl(float2& p, int mask, float c, float s) {
    float qx = __shfl_xor(p.x, mask);
    float qy = __shfl_xor(p.y, mask);
    p = make_float2(c * p.x + s * qy, c * p.y - s * qx);
}
__device__ __forceinline__ void zz_apply(const Smem& sm, float2& a, int k) {
    int d = (k ^ (k >> 1)) & 0x1FFF;
    float2 rot = cmulf(sm.tabLo[d & 63], sm.tabHi[d >> 6]);
    a = cmulf(a, rot);
}
__device__ __forceinline__ void stage_12(float2* slab, float2 r[4], int t) {
    __syncthreads();
#pragma unroll
    for (int j = 0; j < 4; ++j) slab[(t << 2) | j] = r[j];
    __syncthreads();
#pragma unroll
    for (int j = 0; j < 4; ++j) r[j] = slab[t | (j << 8)];
}
__device__ __forceinline__ void stage_21(float2* slab, float2 r[4], int t) {
    __syncthreads();
#pragma unroll
    for (int j = 0; j < 4; ++j) slab[t | (j << 8)] = r[j];
    __syncthreads();
#pragma unroll
    for (int j = 0; j < 4; ++j) r[j] = slab[(t << 2) | j];
}
__device__ __forceinline__ void reduce_qubit(Smem& sm, int sb, int i, int t) {
    float cr = 0.f, ci = 0.f, z = 0.f;
#pragma unroll
    for (int j = 0; j < 4; ++j) {
        const int m = (t << 2) | j;
        const float2 a = sm.slab[m];
        const float n = a.x * a.x + a.y * a.y;
        if ((m >> sb) & 1) {
            z -= n;
        } else {
            z += n;
            const float2 b = sm.slab[m ^ (1 << sb)];
            cr += a.x * b.x + a.y * b.y;
            ci += a.x * b.y - a.y * b.x;
        }
    }
#pragma unroll
    for (int off = 32; off; off >>= 1) {
        cr += __shfl_down(cr, off);
        ci += __shfl_down(ci, off);
        z  += __shfl_down(z, off);
    }
    if ((t & 63) == 0) {
        atomicAdd(&sm.red[3 * i + 0], cr);
        atomicAdd(&sm.red[3 * i + 1], ci);
        atomicAdd(&sm.red[3 * i + 2], z);
    }
}

// Layout A: k = (w<<10)|m, slab bit b == qubit b (WG rank w = qubits 10..13).
template <bool F, bool FIRST>
__device__ void phaseA(Smem& sm, float2* psi, int w, int t,
                       const float* c, const float* s) {
    float2 r[4];
    if (FIRST) {
#pragma unroll
        for (int j = 0; j < 4; ++j) r[j] = make_float2(0.0078125f, 0.0f);
    } else {
        ld4c<F>(&psi[(w << 10) | (t << 2)], r);
        bfly(r[0], r[1], c[0], s[0]); bfly(r[2], r[3], c[0], s[0]);
        bfly(r[0], r[2], c[1], s[1]); bfly(r[1], r[3], c[1], s[1]);
#pragma unroll
        for (int j = 0; j < 4; ++j) bfly_shfl(r[j], 1, c[2], s[2]);
#pragma unroll
        for (int j = 0; j < 4; ++j) bfly_shfl(r[j], 2, c[3], s[3]);
    }
#pragma unroll
    for (int j = 0; j < 4; ++j) zz_apply(sm, r[j], (w << 10) | (t << 2) | j);
    bfly(r[0], r[1], c[0], s[0]); bfly(r[2], r[3], c[0], s[0]);
    bfly(r[0], r[2], c[1], s[1]); bfly(r[1], r[3], c[1], s[1]);
#pragma unroll
    for (int b = 0; b < 6; ++b) {
#pragma unroll
        for (int j = 0; j < 4; ++j) bfly_shfl(r[j], 1 << b, c[2 + b], s[2 + b]);
    }
    stage_12(sm.slab, r, t);
    bfly(r[0], r[1], c[8], s[8]); bfly(r[2], r[3], c[8], s[8]);
    bfly(r[0], r[2], c[9], s[9]); bfly(r[1], r[3], c[9], s[9]);
#pragma unroll
    for (int j = 0; j < 4; ++j) st2<F>(&psi[(w << 10) | t | (j << 8)], r[j]);
}

// Layout B: k = (m<<4)|w, slab bit b == qubit b+4 (WG rank w = qubits 0..3).
template <bool F, bool REDUCE>
__device__ void phaseB(Smem& sm, float2* psi, int w, int t,
                       const float* c, const float* s) {
    float2 r[4];
    ld4s<F>(&psi[((t << 2) << 4) | w],       &psi[(((t << 2) | 1) << 4) | w],
            &psi[(((t << 2) | 2) << 4) | w], &psi[(((t << 2) | 3) << 4) | w], r);
#pragma unroll
    for (int j = 0; j < 4; ++j) bfly_shfl(r[j], 16, c[10], s[10]);
#pragma unroll
    for (int j = 0; j < 4; ++j) bfly_shfl(r[j], 32, c[11], s[11]);
    stage_12(sm.slab, r, t);
    bfly(r[0], r[1], c[12], s[12]); bfly(r[2], r[3], c[12], s[12]);
    bfly(r[0], r[2], c[13], s[13]); bfly(r[1], r[3], c[13], s[13]);
#pragma unroll
    for (int j = 0; j < 4; ++j) zz_apply(sm, r[j], ((t | (j << 8)) << 4) | w);
    bfly(r[0], r[1], c[12], s[12]); bfly(r[2], r[3], c[12], s[12]);
    bfly(r[0], r[2], c[13], s[13]); bfly(r[1], r[3], c[13], s[13]);
#pragma unroll
    for (int b = 0; b < 6; ++b) {
#pragma unroll
        for (int j = 0; j < 4; ++j) bfly_shfl(r[j], 1 << b, c[4 + b], s[4 + b]);
    }
    stage_21(sm.slab, r, t);
#pragma unroll
    for (int j = 0; j < 4; ++j) bfly_shfl(r[j], 16, c[10], s[10]);
#pragma unroll
    for (int j = 0; j < 4; ++j) bfly_shfl(r[j], 32, c[11], s[11]);
#pragma unroll
    for (int j = 0; j < 4; ++j) st2<F>(&psi[(((t << 2) | j) << 4) | w], r[j]);

    if (REDUCE) {
#pragma unroll
        for (int j = 0; j < 4; ++j) sm.slab[(t << 2) | j] = r[j];
        __syncthreads();
#pragma unroll
        for (int q = 10; q <= 13; ++q) reduce_qubit(sm, q - 4, 13 - q, t);
    }
}

// Final phase (A): leftover RX_10{0..3} + q=0..9 reductions; store all 42
// partials TRANSPOSED: P[e*16 + rank].
template <bool F>
__device__ void phaseA_final(Smem& sm, const float2* psi, int w, int t,
                             const float* c, const float* s, float* P) {
    float2 r[4];
    ld4c<F>(&psi[(w << 10) | (t << 2)], r);
    bfly(r[0], r[1], c[0], s[0]); bfly(r[2], r[3], c[0], s[0]);
    bfly(r[0], r[2], c[1], s[1]); bfly(r[1], r[3], c[1], s[1]);
#pragma unroll
    for (int j = 0; j < 4; ++j) bfly_shfl(r[j], 1, c[2], s[2]);
#pragma unroll
    for (int j = 0; j < 4; ++j) bfly_shfl(r[j], 2, c[3], s[3]);
    __syncthreads();
#pragma unroll
    for (int j = 0; j < 4; ++j) sm.slab[(t << 2) | j] = r[j];
    __syncthreads();
#pragma unroll
    for (int q = 0; q <= 9; ++q) reduce_qubit(sm, q, 13 - q, t);
    __syncthreads();
    if (t < 42) stf<F>(&P[t * NWG + w], sm.red[t]);
}

// ================= main templated body ======================================
template <bool F>
__device__ void qr_main(Smem& sm, const float* x, float* out, float2* psi,
                        int* flags, float* P, int rank, int t,
                        const float* cc, const float* ss,
                        int row0, int rows) {
    int bar = 0;
    phaseA<F, true>(sm, psi, rank, t, cc, ss);
    gbar<F>(flags, rank, ++bar);
    for (int sstep = 1; sstep <= 9; ++sstep) {
        if (sstep & 1) {
            if (sstep == 9) phaseB<F, true >(sm, psi, rank, t, cc, ss);
            else            phaseB<F, false>(sm, psi, rank, t, cc, ss);
        } else {
            phaseA<F, false>(sm, psi, rank, t, cc, ss);
        }
        gbar<F>(flags, rank, ++bar);
    }
    phaseA_final<F>(sm, psi, rank, t, cc, ss, P);
    gbar<F>(flags, rank, ++bar);

    // consts: coalesced load of all 672 partials -> LDS -> 42 sums
    float* sumbuf = (float*)sm.slab;
    for (int idx = t; idx < 42 * NWG; idx += NTHR) sumbuf[idx] = ldf<F>(&P[idx]);
    __syncthreads();
    float cv = 0.0f;
    if (t < 42) {
#pragma unroll
        for (int k = 0; k < NWG; ++k) cv += sumbuf[t * NWG + k];
    }
    __syncthreads();
    if (t < 42) sm.red[t] = cv;
    __syncthreads();

    // epilogue: this team's slice of the batch
    const int ntask = rows * NQ;
    for (int task = rank * NTHR + t; task < ntask; task += NWG * NTHR) {
        const int b = row0 + task / NQ;
        const int i = task - (task / NQ) * NQ;
        const int q = 13 - i;
        const float xv = x[b * NQ + q];
        const float cr = sm.red[3 * i + 0];
        const float ci = sm.red[3 * i + 1];
        const float zz = sm.red[3 * i + 2];
        float sn, cs; __sincosf(xv, &sn, &cs);
        float* o = out + b * (3 * NQ) + 3 * i;
        o[0] = 2.0f * (cs * cr - sn * ci);
        o[1] = 2.0f * (sn * cr + cs * ci);
        o[2] = zz;
    }
}

extern "C" __global__ void __launch_bounds__(NTHR)
qr_all(const float* __restrict__ x, const float* __restrict__ J,
       const float* __restrict__ g, float* __restrict__ out,
       char* __restrict__ ws, char* __restrict__ ctrlbase, int tshift) {
    __shared__ Smem sm;
    const int t = threadIdx.x;
    const int nteams = 1 << tshift;
    const int team = blockIdx.x & (nteams - 1);
    const int rank = blockIdx.x >> tshift;
    const float dt = 0.1f;

    float2* psi = (float2*)(ws + (size_t)team * TEAM_PSI_BYTES);
    char* tc   = ctrlbase + team * CTRL_STRIDE;
    int* flags = (int*)tc;
    int* probe = (int*)(tc + 64);
    int* c1    = (int*)(tc + 128);
    int* c2    = (int*)(tc + 132);
    int* go    = (int*)(tc + 136);
    int* fail  = (int*)(tc + 140);
    float* P   = (float*)(tc + 192);

    // --- coherence probe (t==255): is this WG on the leader's XCD? --------
    if (t == 255) {
        (void)ldi<true>(probe);   // prime this XCD's L2 with the zeroed line
        __hip_atomic_fetch_add(c1, 1, __ATOMIC_RELAXED, __HIP_MEMORY_SCOPE_AGENT);
        while (__hip_atomic_load(c1, __ATOMIC_RELAXED, __HIP_MEMORY_SCOPE_AGENT) < NWG)
            __builtin_amdgcn_s_sleep(1);
        if (rank == 0) {
            sti<true>(probe, PROBE_MAGIC);   // sc0: write-through to OUR L2
            asm volatile("s_waitcnt vmcnt(0)" ::: "memory");
            __hip_atomic_store(go, 1, __ATOMIC_RELAXED, __HIP_MEMORY_SCOPE_AGENT);
        } else {
            while (__hip_atomic_load(go, __ATOMIC_RELAXED, __HIP_MEMORY_SCOPE_AGENT) == 0)
                __builtin_amdgcn_s_sleep(1);
        }
        if (ldi<true>(probe) != PROBE_MAGIC)   // stale -> different XCD
            __hip_atomic_store(fail, 1, __ATOMIC_RELAXED, __HIP_MEMORY_SCOPE_AGENT);
        __hip_atomic_fetch_add(c2, 1, __ATOMIC_RELAXED, __HIP_MEMORY_SCOPE_AGENT);
        while (__hip_atomic_load(c2, __ATOMIC_RELAXED, __HIP_MEMORY_SCOPE_AGENT) < NWG)
            __builtin_amdgcn_s_sleep(1);
        sm.fastmode =
            (__hip_atomic_load(fail, __ATOMIC_RELAXED, __HIP_MEMORY_SCOPE_AGENT) == 0);
    }

    // --- ZZ tables + RX params (overlap the probe) ------------------------
    if (t < 64) {
        float phi = 0.0f;
        for (int i = 0; i < 6; ++i) {
            const float h = 0.5f * J[i] * dt;
            phi += ((t >> i) & 1) ? h : -h;
        }
        float sn, cs; __sincosf(phi, &sn, &cs);
        sm.tabLo[t] = make_float2(cs, sn);
    } else if (t < 192) {
        const int v = t - 64;
        float phi = 0.0f;
        for (int i = 0; i < 7; ++i) {
            const float h = 0.5f * J[6 + i] * dt;
            phi += ((v >> i) & 1) ? h : -h;
        }
        float sn, cs; __sincosf(phi, &sn, &cs);
        sm.tabHi[v] = make_float2(cs, sn);
    }
    if (t < 48) sm.red[t] = 0.0f;
    float cc[NQ], ss[NQ];
#pragma unroll
    for (int i = 0; i < NQ; ++i) __sincosf(0.5f * g[i] * dt, &ss[i], &cc[i]);
    __syncthreads();

    const int rows = 2048 >> tshift;
    const int row0 = team * rows;
    if (sm.fastmode)
        qr_main<true >(sm, x, out, psi, flags, P, rank, t, cc, ss, row0, rows);
    else
        qr_main<false>(sm, x, out, psi, flags, P, rank, t, cc, ss, row0, rows);
}

extern "C" void kernel_launch(void* const* d_in, const int* in_sizes, int n_in,
                              void* d_out, int out_size, void* d_ws, size_t ws_size,
                              hipStream_t stream) {
    const float* x = (const float*)d_in[0];
    const float* J = (const float*)d_in[1];
    const float* g = (const float*)d_in[2];
    float* out = (float*)d_out;
    char* ws   = (char*)d_ws;
    (void)in_sizes; (void)n_in; (void)out_size;

    // teams = largest power of two (<=8) whose psi+control fits in d_ws
    int tshift = 3;
    while (tshift > 0 &&
           ((size_t)(1 << tshift)) * (TEAM_PSI_BYTES + CTRL_STRIDE) > ws_size)
        --tshift;
    const int nteams = 1 << tshift;
    char* ctrlbase = ws + (size_t)nteams * TEAM_PSI_BYTES;

    // zero all team control blocks (flags/probe/counters); psi needs no init
    hipMemsetAsync(ctrlbase, 0, (size_t)nteams * CTRL_STRIDE, stream);
    hipLaunchKernelGGL(qr_all, dim3(nteams * NWG), dim3(NTHR), 0, stream,
                       x, J, g, out, ws, ctrlbase, tshift);
}

// Round 7
// 106.275 us; speedup vs baseline: 1.0988x; 1.0988x over previous
//
#include <hip/hip_runtime.h>

#define NQ     14
#define DIMQ   16384
#define NTROT  10
#define NWG    16
#define NTHR   256

typedef float vfloat4 __attribute__((ext_vector_type(4)));

struct Smem {
    float2 slab[1024];   // 8 KiB staging slab (reused as float sumbuf)
    float2 tabLo[64];    // e^{i phi} for ZZ couplers 0..5
    float2 tabHi[128];   // e^{i phi} for ZZ couplers 6..12
    float  red[48];      // this WG's partial sums of the 42 constants
};

// ---------- device-coherent accessors (sc0 sc1 = agent scope, proven) ------
__device__ __forceinline__ float2 d2f2(double d) { union { double d; float2 f; } u; u.d = d; return u.f; }
__device__ __forceinline__ double f22d(float2 f) { union { double d; float2 f; } u; u.f = f; return u.d; }

// 4 contiguous float2 (32 B): two dwordx4, one waitcnt
__device__ __forceinline__ void ld4c(const float2* p, float2 r[4]) {
    vfloat4 a, b;
    asm volatile("global_load_dwordx4 %0, %2, off sc0 sc1\n\t"
                 "global_load_dwordx4 %1, %2, off offset:16 sc0 sc1\n\t"
                 "s_waitcnt vmcnt(0)"
                 : "=&v"(a), "=&v"(b) : "v"(p) : "memory");
    r[0] = make_float2(a.x, a.y); r[1] = make_float2(a.z, a.w);
    r[2] = make_float2(b.x, b.y); r[3] = make_float2(b.z, b.w);
}
// 4 contiguous float2 store
__device__ __forceinline__ void st4c(float2* p, const float2 r[4]) {
    vfloat4 a, b;
    a.x = r[0].x; a.y = r[0].y; a.z = r[1].x; a.w = r[1].y;
    b.x = r[2].x; b.y = r[2].y; b.z = r[3].x; b.w = r[3].y;
    asm volatile("global_store_dwordx4 %0, %1, off sc0 sc1\n\t"
                 "global_store_dwordx4 %0, %2, off offset:16 sc0 sc1"
                 : : "v"(p), "v"(a), "v"(b) : "memory");
}
__device__ __forceinline__ void st2(float2* p, float2 v) {
    asm volatile("global_store_dwordx2 %0, %1, off sc0 sc1"
                 : : "v"(p), "v"(f22d(v)) : "memory");
}
__device__ __forceinline__ void stf(float* p, float v) {
    asm volatile("global_store_dword %0, %1, off sc0 sc1" : : "v"(p), "v"(v) : "memory");
}
__device__ __forceinline__ float ldf(const float* p) {
    float v;
    asm volatile("global_load_dword %0, %1, off sc0 sc1\n\ts_waitcnt vmcnt(0)"
                 : "=&v"(v) : "v"(p) : "memory");
    return v;
}
__device__ __forceinline__ void sti(int* p, int v) {
    asm volatile("global_store_dword %0, %1, off sc0 sc1" : : "v"(p), "v"(v) : "memory");
}
__device__ __forceinline__ int ldi(const int* p) {
    int v;
    asm volatile("global_load_dword %0, %1, off sc0 sc1\n\ts_waitcnt vmcnt(0)"
                 : "=&v"(v) : "v"(p) : "memory");
    return v;
}

// Flag-array barrier. EXPLICIT vmcnt drain: psi stores are inline asm, which
// the compiler's waitcnt tracking cannot see. Phase-numbered flags: the 0xAA
// workspace poison is negative, so no zero-init is needed.
__device__ __forceinline__ void gbar(int* flags, int w, int phase) {
    asm volatile("s_waitcnt vmcnt(0)" ::: "memory");
    __syncthreads();
    if (threadIdx.x < 64) {
        if (threadIdx.x == 0) sti(&flags[w], phase);
        for (;;) {
            int v = phase;
            if (threadIdx.x < NWG) v = ldi(&flags[threadIdx.x]);
            if (__ballot(v >= phase) == ~0ull) break;
            __builtin_amdgcn_s_sleep(1);
        }
    }
    __syncthreads();
}

// ---------------- gate math ------------------------------------------------
__device__ __forceinline__ float2 cmulf(float2 a, float2 b) {
    return make_float2(a.x * b.x - a.y * b.y, a.x * b.y + a.y * b.x);
}
__device__ __forceinline__ void bfly(float2& p0, float2& p1, float c, float s) {
    float2 n0 = make_float2(c * p0.x + s * p1.y, c * p0.y - s * p1.x);
    float2 n1 = make_float2(c * p1.x + s * p0.y, c * p1.y - s * p0.x);
    p0 = n0; p1 = n1;
}
__device__ __forceinline__ void bfly_shfl(float2& p, int mask, float c, float s) {
    float qx = __shfl_xor(p.x, mask);
    float qy = __shfl_xor(p.y, mask);
    p = make_float2(c * p.x + s * qy, c * p.y - s * qx);
}
__device__ __forceinline__ void zz_apply(const Smem& sm, float2& a, int k) {
    int d = (k ^ (k >> 1)) & 0x1FFF;
    float2 rot = cmulf(sm.tabLo[d & 63], sm.tabHi[d >> 6]);
    a = cmulf(a, rot);
}
// mapping1: m=(t<<2)|j (regs = m bits 0,1)  <->  mapping2: m=t|(j<<8) (regs = m bits 8,9)
__device__ __forceinline__ void stage_12(float2* slab, float2 r[4], int t) {
    __syncthreads();
#pragma unroll
    for (int j = 0; j < 4; ++j) slab[(t << 2) | j] = r[j];
    __syncthreads();
#pragma unroll
    for (int j = 0; j < 4; ++j) r[j] = slab[t | (j << 8)];
}
__device__ __forceinline__ void stage_21(float2* slab, float2 r[4], int t) {
    __syncthreads();
#pragma unroll
    for (int j = 0; j < 4; ++j) slab[t | (j << 8)] = r[j];
    __syncthreads();
#pragma unroll
    for (int j = 0; j < 4; ++j) r[j] = slab[(t << 2) | j];
}
// Reduce triple i over the WG's slab; qubit at slab bit sb.
__device__ __forceinline__ void reduce_qubit(Smem& sm, int sb, int i, int t) {
    float cr = 0.f, ci = 0.f, z = 0.f;
#pragma unroll
    for (int j = 0; j < 4; ++j) {
        const int m = (t << 2) | j;
        const float2 a = sm.slab[m];
        const float n = a.x * a.x + a.y * a.y;
        if ((m >> sb) & 1) {
            z -= n;
        } else {
            z += n;
            const float2 b = sm.slab[m ^ (1 << sb)];
            cr += a.x * b.x + a.y * b.y;
            ci += a.x * b.y - a.y * b.x;
        }
    }
#pragma unroll
    for (int off = 32; off; off >>= 1) {
        cr += __shfl_down(cr, off);
        ci += __shfl_down(ci, off);
        z  += __shfl_down(z, off);
    }
    if ((t & 63) == 0) {
        atomicAdd(&sm.red[3 * i + 0], cr);
        atomicAdd(&sm.red[3 * i + 1], ci);
        atomicAdd(&sm.red[3 * i + 2], z);
    }
}

// ---- Layout A: k = (w<<10)|m. WG w = qubits 10..13; local = qubits 0..9.
// mapping1: regs q0,q1; lanes q2,q3 (masks 1,2), q4..7 (masks 4,8,16,32);
// wave bits (t>>6) = q8,q9. Leftover from B' = RX_s{4..7}.
template <bool FIRST>
__device__ void phaseA(Smem& sm, float2* psi, int w, int t,
                       const float* c, const float* s) {
    float2 r[4];
    if (FIRST) {
#pragma unroll
        for (int j = 0; j < 4; ++j) r[j] = make_float2(0.0078125f, 0.0f);
    } else {
        ld4c(&psi[(w << 10) | (t << 2)], r);
        // leftover RX_s{4..7}: lane masks 4,8,16,32
#pragma unroll
        for (int b = 2; b < 6; ++b) {
#pragma unroll
            for (int j = 0; j < 4; ++j) bfly_shfl(r[j], 1 << b, c[2 + b], s[2 + b]);
        }
    }
    // ZZ_{s+1} + RX_{s+1}{0..9}
#pragma unroll
    for (int j = 0; j < 4; ++j) zz_apply(sm, r[j], (w << 10) | (t << 2) | j);
    bfly(r[0], r[1], c[0], s[0]); bfly(r[2], r[3], c[0], s[0]);
    bfly(r[0], r[2], c[1], s[1]); bfly(r[1], r[3], c[1], s[1]);
#pragma unroll
    for (int b = 0; b < 6; ++b) {
#pragma unroll
        for (int j = 0; j < 4; ++j) bfly_shfl(r[j], 1 << b, c[2 + b], s[2 + b]);
    }
    stage_12(sm.slab, r, t);   // mapping2: regs = q8,q9
    bfly(r[0], r[1], c[8], s[8]); bfly(r[2], r[3], c[8], s[8]);
    bfly(r[0], r[2], c[9], s[9]); bfly(r[1], r[3], c[9], s[9]);
    // store mapping2: per j, 64 consecutive float2 per wave (coalesced)
#pragma unroll
    for (int j = 0; j < 4; ++j) st2(&psi[(w << 10) | t | (j << 8)], r[j]);
}

// ---- Layout B': k = (hi6<<8)|(w<<4)|lo4. WG w = qubits 4..7;
// local = {0..3, 8..13}. Thread t: kbase = ((t>>2)<<8)|(w<<4)|((t&3)<<2),
// r[j] = psi[kbase+j] -> CONTIGUOUS 32 B per thread, 128-B line-aligned chunks.
// mapping1: regs q0,q1; lanes q2,q3 (1,2), q8,q9 (4,8), q10,q11 (16,32);
// wave = q12,q13.  mapping2 (m=t|(j<<8)): regs q12,q13; lanes q0..3 (1,2,4,8),
// q8,q9 (16,32); wave = q10,q11.
// Does: RX_s{10..13}, ZZ_{s+1}, RX_{s+1}{0..3, 8..13}. Leftover: RX_{s+1}{4..7}.
// If REDUCE: expectations for all q NOT in {4..7} (leftover commutes).
template <bool REDUCE>
__device__ void phaseB(Smem& sm, float2* psi, int w, int t,
                       const float* c, const float* s) {
    float2 r[4];
    const int kbase = ((t >> 2) << 8) | (w << 4) | ((t & 3) << 2);
    ld4c(&psi[kbase], r);
    // finish step s: RX_s{10,11} (masks 16,32), then q12,13 via mapping2
#pragma unroll
    for (int j = 0; j < 4; ++j) bfly_shfl(r[j], 16, c[10], s[10]);
#pragma unroll
    for (int j = 0; j < 4; ++j) bfly_shfl(r[j], 32, c[11], s[11]);
    stage_12(sm.slab, r, t);   // mapping2: regs = q12,q13
    bfly(r[0], r[1], c[12], s[12]); bfly(r[2], r[3], c[12], s[12]);
    bfly(r[0], r[2], c[13], s[13]); bfly(r[1], r[3], c[13], s[13]);
    // ZZ_{s+1}: k from m = t|(j<<8)
#pragma unroll
    for (int j = 0; j < 4; ++j) {
        const int m = t | (j << 8);
        zz_apply(sm, r[j], ((m >> 4) << 8) | (w << 4) | (m & 15));
    }
    // RX_{s+1}{12,13} (regs), {0..3} (masks 1,2,4,8), {8,9} (masks 16,32)
    bfly(r[0], r[1], c[12], s[12]); bfly(r[2], r[3], c[12], s[12]);
    bfly(r[0], r[2], c[13], s[13]); bfly(r[1], r[3], c[13], s[13]);
#pragma unroll
    for (int b = 0; b < 4; ++b) {
#pragma unroll
        for (int j = 0; j < 4; ++j) bfly_shfl(r[j], 1 << b, c[b], s[b]);
    }
#pragma unroll
    for (int j = 0; j < 4; ++j) bfly_shfl(r[j], 16, c[8], s[8]);
#pragma unroll
    for (int j = 0; j < 4; ++j) bfly_shfl(r[j], 32, c[9], s[9]);
    // RX_{s+1}{10,11}: back to mapping1, masks 16,32
    stage_21(sm.slab, r, t);
#pragma unroll
    for (int j = 0; j < 4; ++j) bfly_shfl(r[j], 16, c[10], s[10]);
#pragma unroll
    for (int j = 0; j < 4; ++j) bfly_shfl(r[j], 32, c[11], s[11]);
    st4c(&psi[kbase], r);   // contiguous store

    if (REDUCE) {
        // slab[(t<<2)|j] was last read by this same thread in stage_21 — safe
#pragma unroll
        for (int j = 0; j < 4; ++j) sm.slab[(t << 2) | j] = r[j];
        __syncthreads();
        // local slab bits: q0..3 -> 0..3, q8..13 -> 4..9; triple i = 13-q
#pragma unroll
        for (int q = 0; q <= 3; ++q) reduce_qubit(sm, q, 13 - q, t);
#pragma unroll
        for (int q = 8; q <= 13; ++q) reduce_qubit(sm, q - 4, 13 - q, t);
    }
}

// Final phase (layout A): leftover RX_10{4..7}, reductions q4..7 only,
// then store all 42 partials transposed: P[e*16 + w]. No psi write-back.
__device__ void phaseA_final(Smem& sm, const float2* psi, int w, int t,
                             const float* c, const float* s, float* P) {
    float2 r[4];
    ld4c(&psi[(w << 10) | (t << 2)], r);
#pragma unroll
    for (int b = 2; b < 6; ++b) {
#pragma unroll
        for (int j = 0; j < 4; ++j) bfly_shfl(r[j], 1 << b, c[2 + b], s[2 + b]);
    }
    __syncthreads();
#pragma unroll
    for (int j = 0; j < 4; ++j) sm.slab[(t << 2) | j] = r[j];
    __syncthreads();
#pragma unroll
    for (int q = 4; q <= 7; ++q) reduce_qubit(sm, q, 13 - q, t);
    __syncthreads();
    if (t < 42) stf(&P[t * NWG + w], sm.red[t]);
}

extern "C" __global__ void __launch_bounds__(NTHR)
qr_all(const float* __restrict__ x, const float* __restrict__ J,
       const float* __restrict__ g, float* __restrict__ out,
       float2* __restrict__ psi, float* __restrict__ P,
       int* __restrict__ flags) {
    __shared__ Smem sm;
    const int w = blockIdx.x;
    const int t = threadIdx.x;
    const float dt = 0.1f;   // EVO_TIME / N_TROTTER

    if (t < 64) {
        float phi = 0.0f;
        for (int i = 0; i < 6; ++i) {
            const float h = 0.5f * J[i] * dt;
            phi += ((t >> i) & 1) ? h : -h;
        }
        float sn, cs; __sincosf(phi, &sn, &cs);
        sm.tabLo[t] = make_float2(cs, sn);
    } else if (t < 192) {
        const int v = t - 64;
        float phi = 0.0f;
        for (int i = 0; i < 7; ++i) {
            const float h = 0.5f * J[6 + i] * dt;
            phi += ((v >> i) & 1) ? h : -h;
        }
        float sn, cs; __sincosf(phi, &sn, &cs);
        sm.tabHi[v] = make_float2(cs, sn);
    }
    if (t < 48) sm.red[t] = 0.0f;
    float cc[NQ], ss[NQ];
#pragma unroll
    for (int i = 0; i < NQ; ++i) __sincosf(0.5f * g[i] * dt, &ss[i], &cc[i]);
    __syncthreads();

    int bar = 0;
    // Phase 1 (A): init + ZZ_1 + RX_1{0..9}
    phaseA<true>(sm, psi, w, t, cc, ss);
    gbar(flags, w, ++bar);
    // Phases 2..10: B' on even steps, A on odd steps
    for (int sstep = 1; sstep <= 9; ++sstep) {
        if (sstep & 1) {
            if (sstep == 9) phaseB<true >(sm, psi, w, t, cc, ss);
            else            phaseB<false>(sm, psi, w, t, cc, ss);
        } else {
            phaseA<false>(sm, psi, w, t, cc, ss);
        }
        gbar(flags, w, ++bar);
    }
    // Phase 11 (A): leftover RX_10{4..7} + reductions q4..7 + partial store
    phaseA_final(sm, psi, w, t, cc, ss, P);
    gbar(flags, w, ++bar);

    // Epilogue: coalesced gather of 672 partials -> LDS -> 42 sums
    float* sumbuf = (float*)sm.slab;
    for (int idx = t; idx < 42 * NWG; idx += NTHR) sumbuf[idx] = ldf(&P[idx]);
    __syncthreads();
    float cv = 0.0f;
    if (t < 42) {
#pragma unroll
        for (int k = 0; k < NWG; ++k) cv += sumbuf[t * NWG + k];
    }
    __syncthreads();
    if (t < 42) sm.red[t] = cv;
    __syncthreads();

    // Batched outputs
    for (int task = w * NTHR + t; task < 2048 * NQ; task += NWG * NTHR) {
        const int b = task / NQ;
        const int i = task - b * NQ;
        const int q = 13 - i;
        const float xv = x[b * NQ + q];
        const float cr = sm.red[3 * i + 0];
        const float ci = sm.red[3 * i + 1];
        const float zz = sm.red[3 * i + 2];
        float sn, cs; __sincosf(xv, &sn, &cs);
        float* o = out + b * (3 * NQ) + 3 * i;
        o[0] = 2.0f * (cs * cr - sn * ci);
        o[1] = 2.0f * (sn * cr + cs * ci);
        o[2] = zz;
    }
}

extern "C" void kernel_launch(void* const* d_in, const int* in_sizes, int n_in,
                              void* d_out, int out_size, void* d_ws, size_t ws_size,
                              hipStream_t stream) {
    const float* x = (const float*)d_in[0];
    const float* J = (const float*)d_in[1];
    const float* g = (const float*)d_in[2];
    float* out = (float*)d_out;
    char* ws   = (char*)d_ws;
    float2* psi  = (float2*)ws;                                   // 128 KiB
    int*    flags = (int*)(ws + DIMQ * sizeof(float2));           // 16 ints
    float*  P     = (float*)(ws + DIMQ * sizeof(float2) + 256);   // 672 floats
    (void)in_sizes; (void)n_in; (void)out_size; (void)ws_size;

    // Single dispatch; no memset needed (phase-numbered flags, poison-safe).
    hipLaunchKernelGGL(qr_all, dim3(NWG), dim3(NTHR), 0, stream,
                       x, J, g, out, psi, P, flags);
}